// Round 23
// baseline (113.533 us; speedup 1.0000x reference)
//
#include <hip/hip_runtime.h>
#include <math.h>

typedef __attribute__((ext_vector_type(8))) short short8v;   // 8 bf16
typedef __attribute__((ext_vector_type(16))) float f32x16;   // MFMA acc

// ws layout:
//  ushort offsets:
//   basisF (fdft) [cc64][tbl4][kh2][m64][e8]     @ u 0        (262144 u)
//     tbl: 0=cosHi 1=cosLo 2=(-sin)Hi 3=(-sin)Lo ; t = cc*16 + kh*8 + e  (folded, t<1024)
//   basisI (idft) [slab4][tbl4][kh2][t1088][e8]  @ u 262144   (278528 u)
//     tbl: 0=cosHi 1=cosLo 2=sinHi 3=sinLo ; m = slab*16 + kh*8 + e
//  float offsets:
//   XP [z16 = tz*8+part][b16][p2][h8][m64][e64]  @ f 270336   (16777216 f, 67 MB)
//  ushort offsets:
//   YT [b16][tbl4][ch512][m64]                   @ u 34095104 (2097152 u)
//     tbl: 0=YrHi 1=YrLo 2=YiHi 3=YiLo (Yi sign-folded)
#define BF_U 0
#define BI_U 262144
#define XP_F 270336
#define YT_U 34095104

__device__ inline unsigned short bf16_rne(float x) {
    unsigned int u = __float_as_uint(x);
    u += 0x7FFFu + ((u >> 16) & 1u);
    return (unsigned short)(u >> 16);
}
__device__ inline float bf16_f(unsigned short h) {
    return __uint_as_float(((unsigned int)h) << 16);
}

__global__ __launch_bounds__(256) void basis_kernel(float* __restrict__ w) {
    int idx = blockIdx.x * 256 + threadIdx.x;
    const float th = 0.0030679615757712823f; // 2*pi/2048
    unsigned short* bw = (unsigned short*)w;
    if (idx < 65536) {           // fdft tables (folded, t<1024)
        int t = idx >> 6, m = idx & 63;
        int j = (m * t) & 2047;
        float s, c; sincosf(th * (float)j, &s, &c);
        float ns = -s;
        int cc = t >> 4, kh = (t >> 3) & 1, e = t & 7;
        int base = BF_U + cc * 4096 + kh * 512 + m * 8 + e;
        unsigned short chv = bf16_rne(c), shv = bf16_rne(ns);
        bw[base]        = chv;
        bw[base + 1024] = bf16_rne(c - bf16_f(chv));
        bw[base + 2048] = shv;
        bw[base + 3072] = bf16_rne(ns - bf16_f(shv));
    }
    if (idx < 69632) {           // idft tables
        int m = idx / 1088, t = idx - m * 1088;
        int j = (m * t) & 2047;
        float s, c; sincosf(th * (float)j, &s, &c);
        int slab = m >> 4, kh = (m >> 3) & 1, e = m & 7;
        int base = BI_U + (slab * 8 + kh) * 8704 + t * 8 + e;
        unsigned short chv = bf16_rne(c), shv = bf16_rne(s);
        bw[base]         = chv;
        bw[base + 17408] = bf16_rne(c - bf16_f(chv));
        bw[base + 34816] = shv;
        bw[base + 52224] = bf16_rne(s - bf16_f(shv));
    }
}

// Forward folded DFT via bf16-split MFMA (round-7 structure, t in 8 parts).
// Block: 64m x 128ch x one t-eighth; 4 waves (wm2 x wc2), wave = 32m x 64ch.
// Reg-staged LDS dbuf; basis staged through LDS. Grid (chtile4, b16, z16) = 1024.
__global__ __launch_bounds__(256, 2) void fdft_kernel(const float* __restrict__ q,
                                                      const float* __restrict__ k,
                                                      float* __restrict__ ws) {
    const int chtile = blockIdx.x;       // 0..3 (128 ch)
    const int b      = blockIdx.y;
    const int z      = blockIdx.z;       // tz*8 + part
    const int part   = z & 7;
    const float* __restrict__ src = (z >> 3) ? k : q;
    const unsigned short* __restrict__ basisF = (const unsigned short*)ws + BF_U;
    float* __restrict__ xp = ws + XP_F + (size_t)(z * 16 + b) * 65536;

    // per chunk (ushorts): basis 4096 ([tbl][kh][m][e]) + data 8192 ([tbl][kh][ch][e])
    __shared__ __align__(16) unsigned short lds[2][12288];   // 48 KB

    const int tid  = threadIdx.x;
    const int lane = tid & 63;
    const int wv   = tid >> 6;
    const int wm   = wv >> 1, wc = wv & 1;
    const int ml   = lane & 31;
    const int khl  = lane >> 5;

    const int chl = tid & 127;     // staging: thread -> (ch, kh)
    const int kh  = tid >> 7;
    const float* __restrict__ ap = src + (size_t)b * 2048 * 512 + chtile * 128 + chl;

    f32x16 accR0, accR1, accI0, accI1;
#pragma unroll
    for (int i = 0; i < 16; ++i) { accR0[i] = 0.f; accR1[i] = 0.f; accI0[i] = 0.f; accI1[i] = 0.f; }

    float av[8], pv[8];
    short8v bas0, bas1;

    auto LOAD = [&](int s) {
        const int t0 = part * 128 + s * 16 + kh * 8;
#pragma unroll
        for (int e = 0; e < 8; ++e) {
            int t = t0 + e;
            int pr = (t == 0) ? 1024 : 2048 - t;
            av[e] = ap[(size_t)t * 512];
            pv[e] = ap[(size_t)pr * 512];
        }
        const unsigned short* bsrc = basisF + (size_t)(part * 8 + s) * 4096;
        bas0 = *(const short8v*)(bsrc + tid * 8);
        bas1 = *(const short8v*)(bsrc + 2048 + tid * 8);
    };
    auto WRITE = [&](int bf) {
        unsigned short* D = &lds[bf][0];
        *(short8v*)(D + tid * 8)        = bas0;
        *(short8v*)(D + 2048 + tid * 8) = bas1;
        short8v xu, xl, xv, xw;
#pragma unroll
        for (int e = 0; e < 8; ++e) {
            float u = av[e] + pv[e], v = av[e] - pv[e];
            unsigned short uh = bf16_rne(u); unsigned short vh = bf16_rne(v);
            xu[e] = (short)uh; xl[e] = (short)bf16_rne(u - bf16_f(uh));
            xv[e] = (short)vh; xw[e] = (short)bf16_rne(v - bf16_f(vh));
        }
        const int doff = 4096 + (kh * 128 + chl) * 8;
        *(short8v*)(D + doff)        = xu;
        *(short8v*)(D + doff + 2048) = xl;
        *(short8v*)(D + doff + 4096) = xv;
        *(short8v*)(D + doff + 6144) = xw;
    };
    auto COMP = [&](int bf) {
        const unsigned short* L = &lds[bf][0];
        const int aoff = (khl * 64 + wm * 32 + ml) * 8;
        short8v cH = *(const short8v*)(L + aoff);
        short8v cL = *(const short8v*)(L + 1024 + aoff);
        short8v sH = *(const short8v*)(L + 2048 + aoff);
        short8v sL = *(const short8v*)(L + 3072 + aoff);
        const int b0 = 4096 + (khl * 128 + wc * 64 + ml) * 8;
        short8v uH0 = *(const short8v*)(L + b0);
        short8v uL0 = *(const short8v*)(L + b0 + 2048);
        short8v vH0 = *(const short8v*)(L + b0 + 4096);
        short8v vL0 = *(const short8v*)(L + b0 + 6144);
        short8v uH1 = *(const short8v*)(L + b0 + 256);
        short8v uL1 = *(const short8v*)(L + b0 + 256 + 2048);
        short8v vH1 = *(const short8v*)(L + b0 + 256 + 4096);
        short8v vL1 = *(const short8v*)(L + b0 + 256 + 6144);
        accR0 = __builtin_amdgcn_mfma_f32_32x32x16_bf16(cH, uH0, accR0, 0, 0, 0);
        accR0 = __builtin_amdgcn_mfma_f32_32x32x16_bf16(cH, uL0, accR0, 0, 0, 0);
        accR0 = __builtin_amdgcn_mfma_f32_32x32x16_bf16(cL, uH0, accR0, 0, 0, 0);
        accI0 = __builtin_amdgcn_mfma_f32_32x32x16_bf16(sH, vH0, accI0, 0, 0, 0);
        accI0 = __builtin_amdgcn_mfma_f32_32x32x16_bf16(sH, vL0, accI0, 0, 0, 0);
        accI0 = __builtin_amdgcn_mfma_f32_32x32x16_bf16(sL, vH0, accI0, 0, 0, 0);
        accR1 = __builtin_amdgcn_mfma_f32_32x32x16_bf16(cH, uH1, accR1, 0, 0, 0);
        accR1 = __builtin_amdgcn_mfma_f32_32x32x16_bf16(cH, uL1, accR1, 0, 0, 0);
        accR1 = __builtin_amdgcn_mfma_f32_32x32x16_bf16(cL, uH1, accR1, 0, 0, 0);
        accI1 = __builtin_amdgcn_mfma_f32_32x32x16_bf16(sH, vH1, accI1, 0, 0, 0);
        accI1 = __builtin_amdgcn_mfma_f32_32x32x16_bf16(sH, vL1, accI1, 0, 0, 0);
        accI1 = __builtin_amdgcn_mfma_f32_32x32x16_bf16(sL, vH1, accI1, 0, 0, 0);
    };

    LOAD(0); WRITE(0); __syncthreads();
    for (int s = 0; s < 8; ++s) {
        if (s < 7) LOAD(s + 1);
        COMP(s & 1);
        if (s < 7) { WRITE((s + 1) & 1); __syncthreads(); }
    }

    if (part == 0) {   // odd-m correction: u[0] folded a1024 with +1 for all m
        const size_t b1024 = (size_t)b * 2048 * 512 + (size_t)1024 * 512 + chtile * 128;
        float a0 = src[b1024 + wc * 64 + ml];
        float a1 = src[b1024 + wc * 64 + 32 + ml];
#pragma unroll
        for (int reg = 1; reg < 16; reg += 2) { accR0[reg] -= 2.f * a0; accR1[reg] -= 2.f * a1; }
    }

    // epilogue: LDS transpose (stride 129) -> coalesced [p][h][m][e] stores
    float* LF = (float*)(&lds[0][0]);
#pragma unroll 1
    for (int pass = 0; pass < 2; ++pass) {
        __syncthreads();
#pragma unroll
        for (int reg = 0; reg < 16; ++reg) {
            const int m = wm * 32 + (reg & 3) + 8 * (reg >> 2) + 4 * khl;
            const int c0l = wc * 64 + ml;
            LF[m * 129 + c0l]      = pass ? accI0[reg] : accR0[reg];
            LF[m * 129 + c0l + 32] = pass ? accI1[reg] : accR1[reg];
        }
        __syncthreads();
#pragma unroll
        for (int u8 = 0; u8 < 8; ++u8) {
            int unit = tid + u8 * 256;              // 2048 units
            int e4 = unit & 3, h = (unit >> 2) & 7, m = unit >> 5;
            float4 val;
            val.x = LF[m * 129 + ((e4 * 4 + 0) * 8 + h)];
            val.y = LF[m * 129 + ((e4 * 4 + 1) * 8 + h)];
            val.z = LF[m * 129 + ((e4 * 4 + 2) * 8 + h)];
            val.w = LF[m * 129 + ((e4 * 4 + 3) * 8 + h)];
            *(float4*)&xp[pass * 32768 + (h * 64 + m) * 64 + chtile * 16 + e4 * 4] = val;
        }
    }
}

// Middle: per (b,h,x-half). 256 thr = 4 waves (wave -> 8 x-rows).
// S = Q K (complex), tanh, xqkv, scale -> YT (bf16 split, transposed)
__global__ __launch_bounds__(256) void mid_kernel(float* __restrict__ ws) {
    const int h = blockIdx.x, b = blockIdx.y, xh = blockIdx.z;
    unsigned short* __restrict__ YTb = (unsigned short*)ws + YT_U + (size_t)b * 131072;

    __shared__ float Qs[2][32][64];   // Q [xl][e]; reused as T [xl][y]
    __shared__ float Ksw[2][64][64];  // K [m][e] XOR-swizzled [m][e^m]

    const int tid = threadIdx.x;
    for (int slot = tid; slot < 1024; slot += 256) {   // p2 x 32m x 16f4
        int p = slot >> 9, ml = (slot >> 4) & 31, c4 = slot & 15;
        int off = ((p * 8 + h) * 64 + xh * 32 + ml) * 64 + c4 * 4;
        float4 acc = make_float4(0.f, 0.f, 0.f, 0.f);
#pragma unroll
        for (int part = 0; part < 8; ++part) {
            const float4 v = *(const float4*)(ws + XP_F + (size_t)(part * 16 + b) * 65536 + off);
            acc.x += v.x; acc.y += v.y; acc.z += v.z; acc.w += v.w;
        }
        *(float4*)(&Qs[p][ml][c4 * 4]) = acc;
    }
    for (int slot = tid; slot < 2048; slot += 256) {   // p2 x 64m x 16f4
        int p = slot >> 10, ml = (slot >> 4) & 63, c4 = slot & 15;
        int off = ((p * 8 + h) * 64 + ml) * 64 + c4 * 4;
        float4 acc = make_float4(0.f, 0.f, 0.f, 0.f);
#pragma unroll
        for (int part = 0; part < 8; ++part) {
            const float4 v = *(const float4*)(ws + XP_F + (size_t)((8 + part) * 16 + b) * 65536 + off);
            acc.x += v.x; acc.y += v.y; acc.z += v.z; acc.w += v.w;
        }
        Ksw[p][ml][(c4 * 4 + 0) ^ ml] = acc.x;
        Ksw[p][ml][(c4 * 4 + 1) ^ ml] = acc.y;
        Ksw[p][ml][(c4 * 4 + 2) ^ ml] = acc.z;
        Ksw[p][ml][(c4 * 4 + 3) ^ ml] = acc.w;
    }
    __syncthreads();

    const int lane = tid & 63;
    const int wid  = tid >> 6;   // 0..3
    const int xb   = wid * 8;

    float sr[8], si[8];
#pragma unroll
    for (int i = 0; i < 8; ++i) { sr[i] = 0.f; si[i] = 0.f; }
    const int y = lane;
    for (int e = 0; e < 64; ++e) {
        float kr = Ksw[0][y][e ^ y];
        float ki = Ksw[1][y][e ^ y];
#pragma unroll
        for (int i = 0; i < 8; ++i) {
            float qr = Qs[0][xb + i][e];
            float qi = Qs[1][xb + i][e];
            sr[i] += qr * kr; sr[i] -= qi * ki;
            si[i] += qr * ki; si[i] += qi * kr;
        }
    }
    float tr[8], ti[8];
#pragma unroll
    for (int i = 0; i < 8; ++i) { tr[i] = tanhf(sr[i]); ti[i] = tanhf(si[i]); }
    __syncthreads();
#pragma unroll
    for (int i = 0; i < 8; ++i) {
        Qs[0][xb + i][y] = tr[i];
        Qs[1][xb + i][y] = ti[i];
    }
    __syncthreads();

    float vr[8], vi[8];
#pragma unroll
    for (int i = 0; i < 8; ++i) { vr[i] = 0.f; vi[i] = 0.f; }
    const int e = lane;
    for (int yy = 0; yy < 64; ++yy) {
        float kr = Ksw[0][yy][e ^ yy];
        float ki = Ksw[1][yy][e ^ yy];
#pragma unroll
        for (int i = 0; i < 8; ++i) {
            float trr = Qs[0][xb + i][yy];
            float tii = Qs[1][xb + i][yy];
            vr[i] += trr * kr; vr[i] -= tii * ki;
            vi[i] += trr * ki; vi[i] += tii * kr;
        }
    }
#pragma unroll
    for (int i = 0; i < 8; ++i) {
        int x = xh * 32 + xb + i;
        float f = (x == 0 ? 1.0f : 2.0f) * (1.0f / (2048.0f * 4096.0f));
        float yr = f * vr[i];
        float yi = -f * vi[i];     // sign folded: out = P + Q with +sin table
        int off = (h * 64 + e) * 64 + x;
        unsigned short rH = bf16_rne(yr), iH = bf16_rne(yi);
        YTb[off]         = rH;
        YTb[32768 + off] = bf16_rne(yr - bf16_f(rH));
        YTb[65536 + off] = iH;
        YTb[98304 + off] = bf16_rne(yi - bf16_f(iH));
    }
}

// Inverse folded DFT via bf16-split MFMA. Block: 64t x 128ch; 4 waves (wt2 x wcc2),
// wave = 32t x 64ch (2 accs/side). Y staged in LDS from YT (m-slabs of 16, dbuf).
// P=sum cos*Yr, Q=sum sin*Yi; out[t]=P+Q (t<=1024), out[2048-t]=P-Q (1<=t<=1023).
__global__ __launch_bounds__(256, 3) void idft_kernel(const float* __restrict__ ws,
                                                      float* __restrict__ out) {
    const int tt0    = blockIdx.x * 64;   // 0..1024
    const int chtile = blockIdx.y;        // 0..3
    const int b      = blockIdx.z;
    const unsigned short* __restrict__ basisI = (const unsigned short*)ws + BI_U;
    const unsigned short* __restrict__ YTb = (const unsigned short*)ws + YT_U + (size_t)b * 131072;

    // [tbl4][ch128][24] per buffer = 12288 ushorts (stride 24 for alignment + banks)
    __shared__ __align__(16) unsigned short ldsY[2][12288];   // 48 KB

    const int tid  = threadIdx.x;
    const int lane = tid & 63;
    const int wv   = tid >> 6;
    const int wt   = wv >> 1, wcc = wv & 1;
    const int ml   = lane & 31;
    const int khl  = lane >> 5;

    f32x16 accP0, accP1, accQ0, accQ1;
#pragma unroll
    for (int i = 0; i < 16; ++i) { accP0[i] = 0.f; accP1[i] = 0.f; accQ0[i] = 0.f; accQ1[i] = 0.f; }

    const int tblA = tid >> 7;            // staging row A: tables 0,1
    const int chlA = tid & 127;
    short8v sA0, sA1, sB0, sB1;

    auto LOAD = [&](int s) {
        const unsigned short* gA = YTb + tblA * 32768 + (chtile * 128 + chlA) * 64 + s * 16;
        const unsigned short* gB = gA + 2 * 32768;      // tables 2,3
        sA0 = *(const short8v*)(gA);
        sA1 = *(const short8v*)(gA + 8);
        sB0 = *(const short8v*)(gB);
        sB1 = *(const short8v*)(gB + 8);
    };
    auto WRITE = [&](int bf) {
        unsigned short* D = &ldsY[bf][0];
        const int offA = tblA * 3072 + chlA * 24;
        *(short8v*)(D + offA)            = sA0;
        *(short8v*)(D + offA + 8)        = sA1;
        *(short8v*)(D + offA + 2 * 3072)     = sB0;
        *(short8v*)(D + offA + 2 * 3072 + 8) = sB1;
    };
    auto COMP = [&](int bf, int s) {
        const unsigned short* bb = basisI + (s * 8 + khl) * 8704 + (tt0 + wt * 32 + ml) * 8;
        short8v cH = *(const short8v*)(bb);
        short8v cL = *(const short8v*)(bb + 17408);
        short8v sH = *(const short8v*)(bb + 34816);
        short8v sL = *(const short8v*)(bb + 52224);
        const unsigned short* L = &ldsY[bf][0];
        const int b0 = (wcc * 64 + ml) * 24 + khl * 8;
        short8v yrH0 = *(const short8v*)(L + b0);
        short8v yrL0 = *(const short8v*)(L + 3072 + b0);
        short8v yiH0 = *(const short8v*)(L + 6144 + b0);
        short8v yiL0 = *(const short8v*)(L + 9216 + b0);
        const int b1 = b0 + 32 * 24;
        short8v yrH1 = *(const short8v*)(L + b1);
        short8v yrL1 = *(const short8v*)(L + 3072 + b1);
        short8v yiH1 = *(const short8v*)(L + 6144 + b1);
        short8v yiL1 = *(const short8v*)(L + 9216 + b1);
        accP0 = __builtin_amdgcn_mfma_f32_32x32x16_bf16(cH, yrH0, accP0, 0, 0, 0);
        accP0 = __builtin_amdgcn_mfma_f32_32x32x16_bf16(cH, yrL0, accP0, 0, 0, 0);
        accP0 = __builtin_amdgcn_mfma_f32_32x32x16_bf16(cL, yrH0, accP0, 0, 0, 0);
        accQ0 = __builtin_amdgcn_mfma_f32_32x32x16_bf16(sH, yiH0, accQ0, 0, 0, 0);
        accQ0 = __builtin_amdgcn_mfma_f32_32x32x16_bf16(sH, yiL0, accQ0, 0, 0, 0);
        accQ0 = __builtin_amdgcn_mfma_f32_32x32x16_bf16(sL, yiH0, accQ0, 0, 0, 0);
        accP1 = __builtin_amdgcn_mfma_f32_32x32x16_bf16(cH, yrH1, accP1, 0, 0, 0);
        accP1 = __builtin_amdgcn_mfma_f32_32x32x16_bf16(cH, yrL1, accP1, 0, 0, 0);
        accP1 = __builtin_amdgcn_mfma_f32_32x32x16_bf16(cL, yrH1, accP1, 0, 0, 0);
        accQ1 = __builtin_amdgcn_mfma_f32_32x32x16_bf16(sH, yiH1, accQ1, 0, 0, 0);
        accQ1 = __builtin_amdgcn_mfma_f32_32x32x16_bf16(sH, yiL1, accQ1, 0, 0, 0);
        accQ1 = __builtin_amdgcn_mfma_f32_32x32x16_bf16(sL, yiH1, accQ1, 0, 0, 0);
    };

    LOAD(0); WRITE(0); __syncthreads();
    for (int s = 0; s < 4; ++s) {
        if (s < 3) LOAD(s + 1);
        COMP(s & 1, s);
        if (s < 3) { WRITE((s + 1) & 1); __syncthreads(); }
    }

    float* __restrict__ ob = out + (size_t)b * 2048 * 512;
#pragma unroll
    for (int reg = 0; reg < 16; ++reg) {
        const int tL = wt * 32 + (reg & 3) + 8 * (reg >> 2) + 4 * khl;
        const int t  = tt0 + tL;
        const int ch0 = chtile * 128 + wcc * 64 + ml;
        float p0 = accP0[reg], q0 = accQ0[reg];
        float p1 = accP1[reg], q1 = accQ1[reg];
        if (t <= 1024) {
            ob[(size_t)t * 512 + ch0]      = p0 + q0;
            ob[(size_t)t * 512 + ch0 + 32] = p1 + q1;
        }
        if (t >= 1 && t <= 1023) {
            ob[(size_t)(2048 - t) * 512 + ch0]      = p0 - q0;
            ob[(size_t)(2048 - t) * 512 + ch0 + 32] = p1 - q1;
        }
    }
}

extern "C" void kernel_launch(void* const* d_in, const int* in_sizes, int n_in,
                              void* d_out, int out_size, void* d_ws, size_t ws_size,
                              hipStream_t stream) {
    const float* q = (const float*)d_in[0];
    const float* k = (const float*)d_in[1];
    float* ws = (float*)d_ws;      // ~73 MB used
    float* out = (float*)d_out;

    hipLaunchKernelGGL(basis_kernel, dim3(272), dim3(256), 0, stream, ws);
    hipLaunchKernelGGL(fdft_kernel, dim3(4, 16, 16), dim3(256), 0, stream, q, k, ws);
    hipLaunchKernelGGL(mid_kernel, dim3(8, 16, 2), dim3(256), 0, stream, ws);
    hipLaunchKernelGGL(idft_kernel, dim3(17, 4, 16), dim3(256), 0, stream, ws, out);
}

// Round 24
// 88.127 us; speedup vs baseline: 1.2883x; 1.2883x over previous
//
#include <hip/hip_runtime.h>
#include <math.h>

typedef __attribute__((ext_vector_type(8))) short short8v;   // 8 bf16
typedef __attribute__((ext_vector_type(16))) float f32x16;   // MFMA acc

// ws layout:
//  ushort offsets:
//   basisF (fdft) [cc64][tbl4][kh2][m64][e8]     @ u 0        (262144 u)
//     tbl: 0=cosHi 1=cosLo 2=(-sin)Hi 3=(-sin)Lo ; t = cc*16 + kh*8 + e  (folded, t<1024)
//   basisI (idft) [slab4][tbl4][kh2][t1088][e8]  @ u 262144   (278528 u)
//     tbl: 0=cosHi 1=cosLo 2=sinHi 3=sinLo ; m = slab*16 + kh*8 + e
//  float offsets:
//   XP [zz8 = tz*4+part][b16][p2][h8][m64][e64]  @ f 270336   (8388608 f)
//  ushort offsets:
//   YT [b16][tbl4][ch512][m64]                   @ u 17317888 (2097152 u)
//     tbl: 0=YrHi 1=YrLo 2=YiHi 3=YiLo (Yi sign-folded)
#define BF_U 0
#define BI_U 262144
#define XP_F 270336
#define YT_U 17317888

__device__ inline unsigned short bf16_rne(float x) {
    unsigned int u = __float_as_uint(x);
    u += 0x7FFFu + ((u >> 16) & 1u);
    return (unsigned short)(u >> 16);
}
__device__ inline float bf16_f(unsigned short h) {
    return __uint_as_float(((unsigned int)h) << 16);
}

__global__ __launch_bounds__(256) void basis_kernel(float* __restrict__ w) {
    int idx = blockIdx.x * 256 + threadIdx.x;
    const float th = 0.0030679615757712823f; // 2*pi/2048
    unsigned short* bw = (unsigned short*)w;
    if (idx < 65536) {           // fdft tables (folded, t<1024)
        int t = idx >> 6, m = idx & 63;
        int j = (m * t) & 2047;
        float s, c; sincosf(th * (float)j, &s, &c);
        float ns = -s;
        int cc = t >> 4, kh = (t >> 3) & 1, e = t & 7;
        int base = BF_U + cc * 4096 + kh * 512 + m * 8 + e;
        unsigned short chv = bf16_rne(c), shv = bf16_rne(ns);
        bw[base]        = chv;
        bw[base + 1024] = bf16_rne(c - bf16_f(chv));
        bw[base + 2048] = shv;
        bw[base + 3072] = bf16_rne(ns - bf16_f(shv));
    }
    if (idx < 69632) {           // idft tables
        int m = idx / 1088, t = idx - m * 1088;
        int j = (m * t) & 2047;
        float s, c; sincosf(th * (float)j, &s, &c);
        int slab = m >> 4, kh = (m >> 3) & 1, e = m & 7;
        int base = BI_U + (slab * 8 + kh) * 8704 + t * 8 + e;
        unsigned short chv = bf16_rne(c), shv = bf16_rne(s);
        bw[base]         = chv;
        bw[base + 17408] = bf16_rne(c - bf16_f(chv));
        bw[base + 34816] = shv;
        bw[base + 52224] = bf16_rne(s - bf16_f(shv));
    }
}

// Forward folded DFT via bf16-split MFMA (round-7 structure — fastest measured).
// Block: 64m x 128ch x one t-quarter; 4 waves (wm2 x wc2), wave = 32m x 64ch.
// Reg-staged LDS dbuf; basis staged through LDS. Grid (chtile4, b16, z8) = 512.
__global__ __launch_bounds__(256, 2) void fdft_kernel(const float* __restrict__ q,
                                                      const float* __restrict__ k,
                                                      float* __restrict__ ws) {
    const int chtile = blockIdx.x;       // 0..3 (128 ch)
    const int b      = blockIdx.y;
    const int z      = blockIdx.z;       // tz*4 + part
    const int part   = z & 3;
    const float* __restrict__ src = (z >> 2) ? k : q;
    const unsigned short* __restrict__ basisF = (const unsigned short*)ws + BF_U;
    float* __restrict__ xp = ws + XP_F + (size_t)(z * 16 + b) * 65536;

    // per chunk (ushorts): basis 4096 ([tbl][kh][m][e]) + data 8192 ([tbl][kh][ch][e])
    __shared__ __align__(16) unsigned short lds[2][12288];   // 48 KB

    const int tid  = threadIdx.x;
    const int lane = tid & 63;
    const int wv   = tid >> 6;
    const int wm   = wv >> 1, wc = wv & 1;
    const int ml   = lane & 31;
    const int khl  = lane >> 5;

    const int chl = tid & 127;     // staging: thread -> (ch, kh)
    const int kh  = tid >> 7;
    const float* __restrict__ ap = src + (size_t)b * 2048 * 512 + chtile * 128 + chl;

    f32x16 accR0, accR1, accI0, accI1;
#pragma unroll
    for (int i = 0; i < 16; ++i) { accR0[i] = 0.f; accR1[i] = 0.f; accI0[i] = 0.f; accI1[i] = 0.f; }

    float av[8], pv[8];
    short8v bas0, bas1;

    auto LOAD = [&](int s) {
        const int t0 = part * 256 + s * 16 + kh * 8;
#pragma unroll
        for (int e = 0; e < 8; ++e) {
            int t = t0 + e;
            int pr = (t == 0) ? 1024 : 2048 - t;
            av[e] = ap[(size_t)t * 512];
            pv[e] = ap[(size_t)pr * 512];
        }
        const unsigned short* bsrc = basisF + (size_t)(part * 16 + s) * 4096;
        bas0 = *(const short8v*)(bsrc + tid * 8);
        bas1 = *(const short8v*)(bsrc + 2048 + tid * 8);
    };
    auto WRITE = [&](int bf) {
        unsigned short* D = &lds[bf][0];
        *(short8v*)(D + tid * 8)        = bas0;
        *(short8v*)(D + 2048 + tid * 8) = bas1;
        short8v xu, xl, xv, xw;
#pragma unroll
        for (int e = 0; e < 8; ++e) {
            float u = av[e] + pv[e], v = av[e] - pv[e];
            unsigned short uh = bf16_rne(u); unsigned short vh = bf16_rne(v);
            xu[e] = (short)uh; xl[e] = (short)bf16_rne(u - bf16_f(uh));
            xv[e] = (short)vh; xw[e] = (short)bf16_rne(v - bf16_f(vh));
        }
        const int doff = 4096 + (kh * 128 + chl) * 8;
        *(short8v*)(D + doff)        = xu;
        *(short8v*)(D + doff + 2048) = xl;
        *(short8v*)(D + doff + 4096) = xv;
        *(short8v*)(D + doff + 6144) = xw;
    };
    auto COMP = [&](int bf) {
        const unsigned short* L = &lds[bf][0];
        const int aoff = (khl * 64 + wm * 32 + ml) * 8;
        short8v cH = *(const short8v*)(L + aoff);
        short8v cL = *(const short8v*)(L + 1024 + aoff);
        short8v sH = *(const short8v*)(L + 2048 + aoff);
        short8v sL = *(const short8v*)(L + 3072 + aoff);
        const int b0 = 4096 + (khl * 128 + wc * 64 + ml) * 8;
        short8v uH0 = *(const short8v*)(L + b0);
        short8v uL0 = *(const short8v*)(L + b0 + 2048);
        short8v vH0 = *(const short8v*)(L + b0 + 4096);
        short8v vL0 = *(const short8v*)(L + b0 + 6144);
        short8v uH1 = *(const short8v*)(L + b0 + 256);
        short8v uL1 = *(const short8v*)(L + b0 + 256 + 2048);
        short8v vH1 = *(const short8v*)(L + b0 + 256 + 4096);
        short8v vL1 = *(const short8v*)(L + b0 + 256 + 6144);
        accR0 = __builtin_amdgcn_mfma_f32_32x32x16_bf16(cH, uH0, accR0, 0, 0, 0);
        accR0 = __builtin_amdgcn_mfma_f32_32x32x16_bf16(cH, uL0, accR0, 0, 0, 0);
        accR0 = __builtin_amdgcn_mfma_f32_32x32x16_bf16(cL, uH0, accR0, 0, 0, 0);
        accI0 = __builtin_amdgcn_mfma_f32_32x32x16_bf16(sH, vH0, accI0, 0, 0, 0);
        accI0 = __builtin_amdgcn_mfma_f32_32x32x16_bf16(sH, vL0, accI0, 0, 0, 0);
        accI0 = __builtin_amdgcn_mfma_f32_32x32x16_bf16(sL, vH0, accI0, 0, 0, 0);
        accR1 = __builtin_amdgcn_mfma_f32_32x32x16_bf16(cH, uH1, accR1, 0, 0, 0);
        accR1 = __builtin_amdgcn_mfma_f32_32x32x16_bf16(cH, uL1, accR1, 0, 0, 0);
        accR1 = __builtin_amdgcn_mfma_f32_32x32x16_bf16(cL, uH1, accR1, 0, 0, 0);
        accI1 = __builtin_amdgcn_mfma_f32_32x32x16_bf16(sH, vH1, accI1, 0, 0, 0);
        accI1 = __builtin_amdgcn_mfma_f32_32x32x16_bf16(sH, vL1, accI1, 0, 0, 0);
        accI1 = __builtin_amdgcn_mfma_f32_32x32x16_bf16(sL, vH1, accI1, 0, 0, 0);
    };

    LOAD(0); WRITE(0); __syncthreads();
    for (int s = 0; s < 16; ++s) {
        if (s < 15) LOAD(s + 1);
        COMP(s & 1);
        if (s < 15) { WRITE((s + 1) & 1); __syncthreads(); }
    }

    if (part == 0) {   // odd-m correction: u[0] folded a1024 with +1 for all m
        const size_t b1024 = (size_t)b * 2048 * 512 + (size_t)1024 * 512 + chtile * 128;
        float a0 = src[b1024 + wc * 64 + ml];
        float a1 = src[b1024 + wc * 64 + 32 + ml];
#pragma unroll
        for (int reg = 1; reg < 16; reg += 2) { accR0[reg] -= 2.f * a0; accR1[reg] -= 2.f * a1; }
    }

    // epilogue: LDS transpose (stride 129) -> coalesced [p][h][m][e] stores
    float* LF = (float*)(&lds[0][0]);
#pragma unroll 1
    for (int pass = 0; pass < 2; ++pass) {
        __syncthreads();
#pragma unroll
        for (int reg = 0; reg < 16; ++reg) {
            const int m = wm * 32 + (reg & 3) + 8 * (reg >> 2) + 4 * khl;
            const int c0l = wc * 64 + ml;
            LF[m * 129 + c0l]      = pass ? accI0[reg] : accR0[reg];
            LF[m * 129 + c0l + 32] = pass ? accI1[reg] : accR1[reg];
        }
        __syncthreads();
#pragma unroll
        for (int u8 = 0; u8 < 8; ++u8) {
            int unit = tid + u8 * 256;              // 2048 units
            int e4 = unit & 3, h = (unit >> 2) & 7, m = unit >> 5;
            float4 val;
            val.x = LF[m * 129 + ((e4 * 4 + 0) * 8 + h)];
            val.y = LF[m * 129 + ((e4 * 4 + 1) * 8 + h)];
            val.z = LF[m * 129 + ((e4 * 4 + 2) * 8 + h)];
            val.w = LF[m * 129 + ((e4 * 4 + 3) * 8 + h)];
            *(float4*)&xp[pass * 32768 + (h * 64 + m) * 64 + chtile * 16 + e4 * 4] = val;
        }
    }
}

// Middle: per (b,h,x-half). 256 thr = 4 waves (wave -> 8 x-rows).
// S = Q K (complex), tanh, xqkv, scale -> YT (bf16 split, transposed)
__global__ __launch_bounds__(256) void mid_kernel(float* __restrict__ ws) {
    const int h = blockIdx.x, b = blockIdx.y, xh = blockIdx.z;
    unsigned short* __restrict__ YTb = (unsigned short*)ws + YT_U + (size_t)b * 131072;

    __shared__ float Qs[2][32][64];   // Q [xl][e]; reused as T [xl][y]
    __shared__ float Ksw[2][64][64];  // K [m][e] XOR-swizzled [m][e^m]

    const int tid = threadIdx.x;
    for (int slot = tid; slot < 1024; slot += 256) {   // p2 x 32m x 16f4
        int p = slot >> 9, ml = (slot >> 4) & 31, c4 = slot & 15;
        int off = ((p * 8 + h) * 64 + xh * 32 + ml) * 64 + c4 * 4;
        float4 acc = make_float4(0.f, 0.f, 0.f, 0.f);
#pragma unroll
        for (int part = 0; part < 4; ++part) {
            const float4 v = *(const float4*)(ws + XP_F + (size_t)(part * 16 + b) * 65536 + off);
            acc.x += v.x; acc.y += v.y; acc.z += v.z; acc.w += v.w;
        }
        *(float4*)(&Qs[p][ml][c4 * 4]) = acc;
    }
    for (int slot = tid; slot < 2048; slot += 256) {   // p2 x 64m x 16f4
        int p = slot >> 10, ml = (slot >> 4) & 63, c4 = slot & 15;
        int off = ((p * 8 + h) * 64 + ml) * 64 + c4 * 4;
        float4 acc = make_float4(0.f, 0.f, 0.f, 0.f);
#pragma unroll
        for (int part = 0; part < 4; ++part) {
            const float4 v = *(const float4*)(ws + XP_F + (size_t)((4 + part) * 16 + b) * 65536 + off);
            acc.x += v.x; acc.y += v.y; acc.z += v.z; acc.w += v.w;
        }
        Ksw[p][ml][(c4 * 4 + 0) ^ ml] = acc.x;
        Ksw[p][ml][(c4 * 4 + 1) ^ ml] = acc.y;
        Ksw[p][ml][(c4 * 4 + 2) ^ ml] = acc.z;
        Ksw[p][ml][(c4 * 4 + 3) ^ ml] = acc.w;
    }
    __syncthreads();

    const int lane = tid & 63;
    const int wid  = tid >> 6;   // 0..3
    const int xb   = wid * 8;

    float sr[8], si[8];
#pragma unroll
    for (int i = 0; i < 8; ++i) { sr[i] = 0.f; si[i] = 0.f; }
    const int y = lane;
    for (int e = 0; e < 64; ++e) {
        float kr = Ksw[0][y][e ^ y];
        float ki = Ksw[1][y][e ^ y];
#pragma unroll
        for (int i = 0; i < 8; ++i) {
            float qr = Qs[0][xb + i][e];
            float qi = Qs[1][xb + i][e];
            sr[i] += qr * kr; sr[i] -= qi * ki;
            si[i] += qr * ki; si[i] += qi * kr;
        }
    }
    float tr[8], ti[8];
#pragma unroll
    for (int i = 0; i < 8; ++i) { tr[i] = tanhf(sr[i]); ti[i] = tanhf(si[i]); }
    __syncthreads();
#pragma unroll
    for (int i = 0; i < 8; ++i) {
        Qs[0][xb + i][y] = tr[i];
        Qs[1][xb + i][y] = ti[i];
    }
    __syncthreads();

    float vr[8], vi[8];
#pragma unroll
    for (int i = 0; i < 8; ++i) { vr[i] = 0.f; vi[i] = 0.f; }
    const int e = lane;
    for (int yy = 0; yy < 64; ++yy) {
        float kr = Ksw[0][yy][e ^ yy];
        float ki = Ksw[1][yy][e ^ yy];
#pragma unroll
        for (int i = 0; i < 8; ++i) {
            float trr = Qs[0][xb + i][yy];
            float tii = Qs[1][xb + i][yy];
            vr[i] += trr * kr; vr[i] -= tii * ki;
            vi[i] += trr * ki; vi[i] += tii * kr;
        }
    }
#pragma unroll
    for (int i = 0; i < 8; ++i) {
        int x = xh * 32 + xb + i;
        float f = (x == 0 ? 1.0f : 2.0f) * (1.0f / (2048.0f * 4096.0f));
        float yr = f * vr[i];
        float yi = -f * vi[i];     // sign folded: out = P + Q with +sin table
        int off = (h * 64 + e) * 64 + x;
        unsigned short rH = bf16_rne(yr), iH = bf16_rne(yi);
        YTb[off]         = rH;
        YTb[32768 + off] = bf16_rne(yr - bf16_f(rH));
        YTb[65536 + off] = iH;
        YTb[98304 + off] = bf16_rne(yi - bf16_f(iH));
    }
}

// Inverse folded DFT via bf16-split MFMA. Block: 64t x 128ch; 4 waves (wt2 x wcc2),
// wave = 32t x 64ch (2 accs/side). Y staged in LDS from YT (m-slabs of 16, dbuf).
// P=sum cos*Yr, Q=sum sin*Yi; out[t]=P+Q (t<=1024), out[2048-t]=P-Q (1<=t<=1023).
__global__ __launch_bounds__(256, 3) void idft_kernel(const float* __restrict__ ws,
                                                      float* __restrict__ out) {
    const int tt0    = blockIdx.x * 64;   // 0..1024
    const int chtile = blockIdx.y;        // 0..3
    const int b      = blockIdx.z;
    const unsigned short* __restrict__ basisI = (const unsigned short*)ws + BI_U;
    const unsigned short* __restrict__ YTb = (const unsigned short*)ws + YT_U + (size_t)b * 131072;

    // [tbl4][ch128][24] per buffer = 12288 ushorts (stride 24 for alignment + banks)
    __shared__ __align__(16) unsigned short ldsY[2][12288];   // 48 KB

    const int tid  = threadIdx.x;
    const int lane = tid & 63;
    const int wv   = tid >> 6;
    const int wt   = wv >> 1, wcc = wv & 1;
    const int ml   = lane & 31;
    const int khl  = lane >> 5;

    f32x16 accP0, accP1, accQ0, accQ1;
#pragma unroll
    for (int i = 0; i < 16; ++i) { accP0[i] = 0.f; accP1[i] = 0.f; accQ0[i] = 0.f; accQ1[i] = 0.f; }

    const int tblA = tid >> 7;            // staging row A: tables 0,1
    const int chlA = tid & 127;
    short8v sA0, sA1, sB0, sB1;

    auto LOAD = [&](int s) {
        const unsigned short* gA = YTb + tblA * 32768 + (chtile * 128 + chlA) * 64 + s * 16;
        const unsigned short* gB = gA + 2 * 32768;      // tables 2,3
        sA0 = *(const short8v*)(gA);
        sA1 = *(const short8v*)(gA + 8);
        sB0 = *(const short8v*)(gB);
        sB1 = *(const short8v*)(gB + 8);
    };
    auto WRITE = [&](int bf) {
        unsigned short* D = &ldsY[bf][0];
        const int offA = tblA * 3072 + chlA * 24;
        *(short8v*)(D + offA)            = sA0;
        *(short8v*)(D + offA + 8)        = sA1;
        *(short8v*)(D + offA + 2 * 3072)     = sB0;
        *(short8v*)(D + offA + 2 * 3072 + 8) = sB1;
    };
    auto COMP = [&](int bf, int s) {
        const unsigned short* bb = basisI + (s * 8 + khl) * 8704 + (tt0 + wt * 32 + ml) * 8;
        short8v cH = *(const short8v*)(bb);
        short8v cL = *(const short8v*)(bb + 17408);
        short8v sH = *(const short8v*)(bb + 34816);
        short8v sL = *(const short8v*)(bb + 52224);
        const unsigned short* L = &ldsY[bf][0];
        const int b0 = (wcc * 64 + ml) * 24 + khl * 8;
        short8v yrH0 = *(const short8v*)(L + b0);
        short8v yrL0 = *(const short8v*)(L + 3072 + b0);
        short8v yiH0 = *(const short8v*)(L + 6144 + b0);
        short8v yiL0 = *(const short8v*)(L + 9216 + b0);
        const int b1 = b0 + 32 * 24;
        short8v yrH1 = *(const short8v*)(L + b1);
        short8v yrL1 = *(const short8v*)(L + 3072 + b1);
        short8v yiH1 = *(const short8v*)(L + 6144 + b1);
        short8v yiL1 = *(const short8v*)(L + 9216 + b1);
        accP0 = __builtin_amdgcn_mfma_f32_32x32x16_bf16(cH, yrH0, accP0, 0, 0, 0);
        accP0 = __builtin_amdgcn_mfma_f32_32x32x16_bf16(cH, yrL0, accP0, 0, 0, 0);
        accP0 = __builtin_amdgcn_mfma_f32_32x32x16_bf16(cL, yrH0, accP0, 0, 0, 0);
        accQ0 = __builtin_amdgcn_mfma_f32_32x32x16_bf16(sH, yiH0, accQ0, 0, 0, 0);
        accQ0 = __builtin_amdgcn_mfma_f32_32x32x16_bf16(sH, yiL0, accQ0, 0, 0, 0);
        accQ0 = __builtin_amdgcn_mfma_f32_32x32x16_bf16(sL, yiH0, accQ0, 0, 0, 0);
        accP1 = __builtin_amdgcn_mfma_f32_32x32x16_bf16(cH, yrH1, accP1, 0, 0, 0);
        accP1 = __builtin_amdgcn_mfma_f32_32x32x16_bf16(cH, yrL1, accP1, 0, 0, 0);
        accP1 = __builtin_amdgcn_mfma_f32_32x32x16_bf16(cL, yrH1, accP1, 0, 0, 0);
        accQ1 = __builtin_amdgcn_mfma_f32_32x32x16_bf16(sH, yiH1, accQ1, 0, 0, 0);
        accQ1 = __builtin_amdgcn_mfma_f32_32x32x16_bf16(sH, yiL1, accQ1, 0, 0, 0);
        accQ1 = __builtin_amdgcn_mfma_f32_32x32x16_bf16(sL, yiH1, accQ1, 0, 0, 0);
    };

    LOAD(0); WRITE(0); __syncthreads();
    for (int s = 0; s < 4; ++s) {
        if (s < 3) LOAD(s + 1);
        COMP(s & 1, s);
        if (s < 3) { WRITE((s + 1) & 1); __syncthreads(); }
    }

    float* __restrict__ ob = out + (size_t)b * 2048 * 512;
#pragma unroll
    for (int reg = 0; reg < 16; ++reg) {
        const int tL = wt * 32 + (reg & 3) + 8 * (reg >> 2) + 4 * khl;
        const int t  = tt0 + tL;
        const int ch0 = chtile * 128 + wcc * 64 + ml;
        float p0 = accP0[reg], q0 = accQ0[reg];
        float p1 = accP1[reg], q1 = accQ1[reg];
        if (t <= 1024) {
            ob[(size_t)t * 512 + ch0]      = p0 + q0;
            ob[(size_t)t * 512 + ch0 + 32] = p1 + q1;
        }
        if (t >= 1 && t <= 1023) {
            ob[(size_t)(2048 - t) * 512 + ch0]      = p0 - q0;
            ob[(size_t)(2048 - t) * 512 + ch0 + 32] = p1 - q1;
        }
    }
}

extern "C" void kernel_launch(void* const* d_in, const int* in_sizes, int n_in,
                              void* d_out, int out_size, void* d_ws, size_t ws_size,
                              hipStream_t stream) {
    const float* q = (const float*)d_in[0];
    const float* k = (const float*)d_in[1];
    float* ws = (float*)d_ws;      // ~38.8 MB used
    float* out = (float*)d_out;

    hipLaunchKernelGGL(basis_kernel, dim3(272), dim3(256), 0, stream, ws);
    hipLaunchKernelGGL(fdft_kernel, dim3(4, 16, 8), dim3(256), 0, stream, q, k, ws);
    hipLaunchKernelGGL(mid_kernel, dim3(8, 16, 2), dim3(256), 0, stream, ws);
    hipLaunchKernelGGL(idft_kernel, dim3(17, 4, 16), dim3(256), 0, stream, ws, out);
}